// Round 1
// baseline (642.433 us; speedup 1.0000x reference)
//
#include <hip/hip_runtime.h>
#include <stdint.h>

// ---------------- types / helpers ----------------
typedef __attribute__((ext_vector_type(4))) float f32x4;
typedef __attribute__((ext_vector_type(8))) short short8;
typedef __attribute__((ext_vector_type(4))) short short4v;

__device__ __forceinline__ short f2bf(float f) {
  union { float f; uint32_t u; } v; v.f = f;
  uint32_t r = v.u + 0x7FFFu + ((v.u >> 16) & 1u);
  return (short)(r >> 16);
}

__device__ __forceinline__ f32x4 mfma16(short8 a, short8 b, f32x4 c) {
  return __builtin_amdgcn_mfma_f32_16x16x32_bf16(a, b, c, 0, 0, 0);
}

#define NB 8
#define LQ 2048
#define LKV 4096
#define DQ 256
#define FF 1024

// ---------------- weight transpose + bf16 cast: out[C][R] = in[R][C] ----------------
__global__ void transpose_cast(const float* __restrict__ in, short* __restrict__ out, int R, int C) {
  __shared__ float t[32][33];
  int c0 = blockIdx.x * 32, r0 = blockIdx.y * 32;
  int tx = threadIdx.x, ty = threadIdx.y;  // 32 x 8
#pragma unroll
  for (int dy = 0; dy < 32; dy += 8)
    t[ty + dy][tx] = in[(long)(r0 + ty + dy) * C + c0 + tx];
  __syncthreads();
#pragma unroll
  for (int dy = 0; dy < 32; dy += 8)
    out[(long)(c0 + ty + dy) * R + r0 + tx] = f2bf(t[tx][ty + dy]);
}

// ---------------- staged tile load: [128 rows][64 k] bf16, XOR-swizzled ----------------
template <bool SRCF32>
__device__ __forceinline__ void stage64(const void* src, int ld, long row0, int k0, char* lds, int tid) {
#pragma unroll
  for (int it = 0; it < 4; ++it) {
    int idx = it * 2048 + tid * 8;
    int r = idx >> 6, c = idx & 63;
    short8 v;
    if (SRCF32) {
      const float* p = (const float*)src + (row0 + r) * (long)ld + k0 + c;
      f32x4 f0 = *(const f32x4*)p;
      f32x4 f1 = *(const f32x4*)(p + 4);
#pragma unroll
      for (int j = 0; j < 4; ++j) { v[j] = f2bf(f0[j]); v[4 + j] = f2bf(f1[j]); }
    } else {
      const short* p = (const short*)src + (row0 + r) * (long)ld + k0 + c;
      v = *(const short8*)p;
    }
    *(short8*)(lds + ((r * 128 + c * 2) ^ ((r & 7) << 4))) = v;
  }
}

// ---------------- generic GEMM: C[M,N] = A[M,K] * B[N,K]^T (+epilogues) ----------------
// EPI: 0 = bf16 out + bias[col]; 1 = bf16 out + bias[row]; 2 = f32 out + bias[col] + resid; 3 = relu bf16 + bias[col]
template <bool AF32, bool BF32, int EPI>
__global__ void __launch_bounds__(256, 2) gemm128(
    const void* __restrict__ A, long sAb, int lda,
    const void* __restrict__ B, long sBb, int ldb,
    const float* __restrict__ bias,
    const float* resid, long sRb,
    void* C, long sCb, int ldc, int K) {
  __shared__ char lds[32768];
  const int tid = threadIdx.x;
  const int bn = blockIdx.x, bm = blockIdx.y, bz = blockIdx.z;
  const void* Ap = AF32 ? (const void*)((const float*)A + sAb * bz) : (const void*)((const short*)A + sAb * bz);
  const void* Bp = BF32 ? (const void*)((const float*)B + sBb * bz) : (const void*)((const short*)B + sBb * bz);
  const int w = tid >> 6, l = tid & 63;
  const int wm = w & 1, wn = w >> 1;
  const int lr = l & 15, lq = l >> 4;
  f32x4 acc[4][4] = {};
  for (int k0 = 0; k0 < K; k0 += 64) {
    stage64<AF32>(Ap, lda, (long)bm * 128, k0, lds, tid);
    stage64<BF32>(Bp, ldb, (long)bn * 128, k0, lds + 16384, tid);
    __syncthreads();
    short8 af[4][2], bfr[4][2];
#pragma unroll
    for (int i = 0; i < 4; ++i) {
#pragma unroll
      for (int kk = 0; kk < 2; ++kk) {
        int ra = wm * 64 + i * 16 + lr;
        af[i][kk] = *(const short8*)(lds + ((ra * 128 + (kk * 32 + lq * 8) * 2) ^ ((ra & 7) << 4)));
        int rb = wn * 64 + i * 16 + lr;
        bfr[i][kk] = *(const short8*)(lds + 16384 + ((rb * 128 + (kk * 32 + lq * 8) * 2) ^ ((rb & 7) << 4)));
      }
    }
#pragma unroll
    for (int i = 0; i < 4; ++i)
#pragma unroll
      for (int j = 0; j < 4; ++j) {
        acc[i][j] = mfma16(af[i][0], bfr[j][0], acc[i][j]);
        acc[i][j] = mfma16(af[i][1], bfr[j][1], acc[i][j]);
      }
    __syncthreads();
  }
#pragma unroll
  for (int i = 0; i < 4; ++i) {
#pragma unroll
    for (int j = 0; j < 4; ++j) {
#pragma unroll
      for (int r = 0; r < 4; ++r) {
        long row = (long)bm * 128 + wm * 64 + i * 16 + lq * 4 + r;
        long col = (long)bn * 128 + wn * 64 + j * 16 + lr;
        float v = acc[i][j][r];
        if (EPI == 0) {
          v += bias[col];
          ((short*)C + sCb * bz)[row * ldc + col] = f2bf(v);
        } else if (EPI == 1) {
          v += bias[row];
          ((short*)C + sCb * bz)[row * ldc + col] = f2bf(v);
        } else if (EPI == 2) {
          v += bias[col] + (resid + sRb * bz)[row * ldc + col];
          ((float*)C + sCb * bz)[row * ldc + col] = v;
        } else {
          v += bias[col];
          v = fmaxf(v, 0.f);
          ((short*)C + sCb * bz)[row * ldc + col] = f2bf(v);
        }
      }
    }
  }
}

// ---------------- flash attention ----------------
// grid (32 qtiles, 8 batches); block 256 = 4 waves; each wave owns 16 q rows x 256 d.
// Kb: [B][LKV][256] bf16 ; Vt: [B][256][LKV] bf16 (V' transposed) ; Cb out: [B][LQ][256] bf16
__global__ void __launch_bounds__(256, 2) flash_attn(
    const float* __restrict__ Q, const short* __restrict__ Kb,
    const short* __restrict__ Vt, short* __restrict__ Cb) {
  __shared__ char lds[73728];
  char* kq = lds;           // 32KB: Q (init) then K tile [64][256]
  char* vt = lds + 32768;   // 32KB: V^T tile [256][64]
  char* pl = lds + 65536;   // 8KB : P tiles, 2KB per wave
  const int tid = threadIdx.x;
  const int qt = blockIdx.x, b = blockIdx.y;
  const int w = tid >> 6, l = tid & 63;
  const int lr = l & 15, lq = l >> 4;
  const float* Qp = Q + ((long)b * LQ + qt * 64) * DQ;
  const short* Kp = Kb + (long)b * LKV * DQ;
  const short* Vp = Vt + (long)b * DQ * LKV;

  // stage Q tile [64][256] f32 -> bf16 LDS (swizzled)
#pragma unroll
  for (int it = 0; it < 8; ++it) {
    int idx = it * 2048 + tid * 8;
    int r = idx >> 8, c = idx & 255;
    const float* p = Qp + r * 256 + c;
    f32x4 f0 = *(const f32x4*)p, f1 = *(const f32x4*)(p + 4);
    short8 v;
#pragma unroll
    for (int j = 0; j < 4; ++j) { v[j] = f2bf(f0[j]); v[4 + j] = f2bf(f1[j]); }
    *(short8*)(kq + ((r * 512 + c * 2) ^ ((r & 7) << 4))) = v;
  }
  __syncthreads();
  short8 qf[8];
  {
    int r = w * 16 + lr;
#pragma unroll
    for (int kk = 0; kk < 8; ++kk)
      qf[kk] = *(const short8*)(kq + ((r * 512 + (kk * 32 + lq * 8) * 2) ^ ((r & 7) << 4)));
  }
  __syncthreads();  // Q region will be reused for K tiles

  f32x4 o[16] = {};
  float m_r[4] = {-1e30f, -1e30f, -1e30f, -1e30f};
  float l_r[4] = {0.f, 0.f, 0.f, 0.f};
  const float SC = 0.0625f * 1.4426950408889634f;  // 1/sqrt(256) * log2(e)

  for (int kv0 = 0; kv0 < LKV; kv0 += 64) {
    // stage K tile [64 kv][256 d]
#pragma unroll
    for (int it = 0; it < 8; ++it) {
      int idx = it * 2048 + tid * 8;
      int r = idx >> 8, c = idx & 255;
      short8 v = *(const short8*)(Kp + (long)(kv0 + r) * 256 + c);
      *(short8*)(kq + ((r * 512 + c * 2) ^ ((r & 7) << 4))) = v;
    }
    // stage V^T tile [256 d][64 kv]
#pragma unroll
    for (int it = 0; it < 8; ++it) {
      int idx = it * 2048 + tid * 8;
      int d = idx >> 6, c = idx & 63;
      short8 v = *(const short8*)(Vp + (long)d * LKV + kv0 + c);
      *(short8*)(vt + ((d * 128 + c * 2) ^ ((d & 7) << 4))) = v;
    }
    __syncthreads();

    // S = Q K'^T  (per wave: 16q x 64kv)
    f32x4 s[4] = {};
#pragma unroll
    for (int j = 0; j < 4; ++j) {
      int r = j * 16 + lr;
#pragma unroll
      for (int kk = 0; kk < 8; ++kk) {
        short8 kf = *(const short8*)(kq + ((r * 512 + (kk * 32 + lq * 8) * 2) ^ ((r & 7) << 4)));
        s[j] = mfma16(qf[kk], kf, s[j]);
      }
    }

    // online softmax (base-2). lane holds rows q = w*16 + lq*4 + r, cols j*16+lr.
    float pmat[4][4];
    float alpha[4];
#pragma unroll
    for (int r = 0; r < 4; ++r) {
      float mx = -1e30f;
#pragma unroll
      for (int j = 0; j < 4; ++j) { pmat[j][r] = s[j][r] * SC; mx = fmaxf(mx, pmat[j][r]); }
      mx = fmaxf(mx, __shfl_xor(mx, 1));
      mx = fmaxf(mx, __shfl_xor(mx, 2));
      mx = fmaxf(mx, __shfl_xor(mx, 4));
      mx = fmaxf(mx, __shfl_xor(mx, 8));
      float mn = fmaxf(m_r[r], mx);
      alpha[r] = exp2f(m_r[r] - mn);
      m_r[r] = mn;
      float rs = 0.f;
#pragma unroll
      for (int j = 0; j < 4; ++j) { float pv = exp2f(pmat[j][r] - mn); pmat[j][r] = pv; rs += pv; }
      rs += __shfl_xor(rs, 1);
      rs += __shfl_xor(rs, 2);
      rs += __shfl_xor(rs, 4);
      rs += __shfl_xor(rs, 8);
      l_r[r] = l_r[r] * alpha[r] + rs;
    }
#pragma unroll
    for (int n = 0; n < 16; ++n)
#pragma unroll
      for (int r = 0; r < 4; ++r) o[n][r] *= alpha[r];

    // P -> LDS (bf16), per-wave private 16x64 tile
    char* pw = pl + w * 2048;
#pragma unroll
    for (int j = 0; j < 4; ++j)
#pragma unroll
      for (int r = 0; r < 4; ++r) {
        int qr = lq * 4 + r, col = j * 16 + lr;
        *(short*)(pw + ((qr * 128 + col * 2) ^ ((qr & 7) << 4))) = f2bf(pmat[j][r]);
      }
    short8 ap[2];
#pragma unroll
    for (int kk = 0; kk < 2; ++kk)
      ap[kk] = *(const short8*)(pw + ((lr * 128 + (kk * 32 + lq * 8) * 2) ^ ((lr & 7) << 4)));

    // O += P V'
#pragma unroll
    for (int n = 0; n < 16; ++n) {
      int d = n * 16 + lr;
#pragma unroll
      for (int kk = 0; kk < 2; ++kk) {
        short8 bv = *(const short8*)(vt + ((d * 128 + (kk * 32 + lq * 8) * 2) ^ ((d & 7) << 4)));
        o[n] = mfma16(ap[kk], bv, o[n]);
      }
    }
    __syncthreads();
  }

  float inv[4];
#pragma unroll
  for (int r = 0; r < 4; ++r) inv[r] = 1.f / l_r[r];
  short* Cp = Cb + ((long)b * LQ + qt * 64 + w * 16) * DQ;
#pragma unroll
  for (int n = 0; n < 16; ++n)
#pragma unroll
    for (int r = 0; r < 4; ++r)
      Cp[(lq * 4 + r) * 256 + n * 16 + lr] = f2bf(o[n][r] * inv[r]);
}

// ---------------- layernorm over rows of 256 ----------------
__global__ void __launch_bounds__(256) ln256(
    const float* in, float* outF, short* outB,
    const float* __restrict__ g, const float* __restrict__ be) {
  const int w = threadIdx.x >> 6, l = threadIdx.x & 63;
  const long row = (long)blockIdx.x * 4 + w;
  const float* p = in + row * 256 + l * 4;
  f32x4 x = *(const f32x4*)p;
  float s = x[0] + x[1] + x[2] + x[3];
  float s2 = x[0] * x[0] + x[1] * x[1] + x[2] * x[2] + x[3] * x[3];
#pragma unroll
  for (int mk = 1; mk < 64; mk <<= 1) { s += __shfl_xor(s, mk); s2 += __shfl_xor(s2, mk); }
  float mu = s * (1.f / 256.f);
  float var = s2 * (1.f / 256.f) - mu * mu;
  float rstd = rsqrtf(var + 1e-5f);
  f32x4 gg = *(const f32x4*)(g + l * 4);
  f32x4 bb = *(const f32x4*)(be + l * 4);
  f32x4 y;
#pragma unroll
  for (int k = 0; k < 4; ++k) y[k] = (x[k] - mu) * rstd * gg[k] + bb[k];
  if (outF) *(f32x4*)(outF + row * 256 + l * 4) = y;
  if (outB) {
    short4v yb;
#pragma unroll
    for (int k = 0; k < 4; ++k) yb[k] = f2bf(y[k]);
    *(short4v*)(outB + row * 256 + l * 4) = yb;
  }
}

// ---------------- launcher ----------------
extern "C" void kernel_launch(void* const* d_in, const int* in_sizes, int n_in,
                              void* d_out, int out_size, void* d_ws, size_t ws_size,
                              hipStream_t stream) {
  const float* query = (const float*)d_in[0];
  const float* key   = (const float*)d_in[1];
  const float* value = (const float*)d_in[2];
  const float* Wk  = (const float*)d_in[3];
  const float* bk  = (const float*)d_in[4];
  const float* Wv  = (const float*)d_in[5];
  const float* bv  = (const float*)d_in[6];
  const float* Wo  = (const float*)d_in[7];
  const float* bo  = (const float*)d_in[8];
  const float* g1  = (const float*)d_in[9];
  const float* b1  = (const float*)d_in[10];
  const float* g2  = (const float*)d_in[11];
  const float* b2  = (const float*)d_in[12];
  const float* W1  = (const float*)d_in[13];
  const float* bf1 = (const float*)d_in[14];
  const float* W2  = (const float*)d_in[15];
  const float* bf2 = (const float*)d_in[16];

  char* ws = (char*)d_ws;
  size_t off = 0;
  auto take = [&](size_t bytes) { char* p = ws + off; off += bytes; return p; };
  short* WkT = (short*)take((size_t)256 * 256 * 2);
  short* WvT = (short*)take((size_t)256 * 256 * 2);
  short* WoT = (short*)take((size_t)256 * 256 * 2);
  short* W1T = (short*)take((size_t)1024 * 256 * 2);
  short* W2T = (short*)take((size_t)256 * 1024 * 2);
  short* Kb  = (short*)take((size_t)NB * LKV * DQ * 2);
  short* Vt  = (short*)take((size_t)NB * DQ * LKV * 2);
  short* Cbuf= (short*)take((size_t)NB * LQ * DQ * 2);
  float* Xf  = (float*)take((size_t)NB * LQ * DQ * 4);
  short* Xb  = (short*)take((size_t)NB * LQ * DQ * 2);
  short* Hb  = (short*)take((size_t)NB * LQ * FF * 2);
  (void)ws_size; (void)in_sizes; (void)n_in; (void)out_size;

  dim3 blk(256);
  dim3 tb(32, 8);
  transpose_cast<<<dim3(8, 8),  tb, 0, stream>>>(Wk, WkT, 256, 256);
  transpose_cast<<<dim3(8, 8),  tb, 0, stream>>>(Wv, WvT, 256, 256);
  transpose_cast<<<dim3(8, 8),  tb, 0, stream>>>(Wo, WoT, 256, 256);
  transpose_cast<<<dim3(32, 8), tb, 0, stream>>>(W1, W1T, 256, 1024);
  transpose_cast<<<dim3(8, 32), tb, 0, stream>>>(W2, W2T, 1024, 256);

  // K' = key @ Wk + bk   -> Kb [B*LKV][256] bf16
  gemm128<true, false, 0><<<dim3(2, 256, 1), blk, 0, stream>>>(
      key, 0, 256, WkT, 0, 256, bk, nullptr, 0, Kb, 0, 256, 256);
  // V'^T = (value @ Wv + bv)^T -> Vt [B][256][LKV] bf16  (A = Wv^T, B = value)
  gemm128<false, true, 1><<<dim3(32, 2, 8), blk, 0, stream>>>(
      WvT, 0, 256, value, (long)LKV * 256, 256, bv, nullptr, 0, Vt, (long)256 * LKV, LKV, 256);
  // attention
  flash_attn<<<dim3(32, 8), blk, 0, stream>>>(query, Kb, Vt, Cbuf);
  // attn_out = context @ Wo + bo + query -> Xf f32
  gemm128<false, false, 2><<<dim3(2, 128, 1), blk, 0, stream>>>(
      Cbuf, 0, 256, WoT, 0, 256, bo, query, 0, Xf, 0, 256, 256);
  // x = LN1(Xf) -> Xf (f32, in-place) + Xb (bf16)
  ln256<<<4096, blk, 0, stream>>>(Xf, Xf, Xb, g1, b1);
  // h = relu(x @ W1 + bf1) -> Hb bf16
  gemm128<false, false, 3><<<dim3(8, 128, 1), blk, 0, stream>>>(
      Xb, 0, 256, W1T, 0, 256, bf1, nullptr, 0, Hb, 0, 1024, 256);
  // y = h @ W2 + bf2 + x -> Xf (in-place)
  gemm128<false, false, 2><<<dim3(2, 128, 1), blk, 0, stream>>>(
      Hb, 0, 1024, W2T, 0, 1024, bf2, Xf, 0, Xf, 0, 256, 1024);
  // out = LN2(Xf)
  ln256<<<4096, blk, 0, stream>>>(Xf, (float*)d_out, nullptr, g2, b2);
}